// Round 10
// baseline (438.676 us; speedup 1.0000x reference)
//
#include <hip/hip_runtime.h>

#define ROW_N 2048
#define ROW_K 1024          // zero the 1024 smallest per row
#define HSIZE 1280          // 1024 bins + 4-dword pad per 16 bins (bank-spread)
#define LOFF  1280          // survivor list offset (128 dwords)
#define WSTRIDE 1416        // 1280 + 128 + 8 stagger (mult of 8, %32 == 8)

// Wave-local LDS fence: this wave's ds ops drained (does NOT wait vmcnt).
__device__ __forceinline__ void wfence() {
    asm volatile("s_waitcnt lgkmcnt(0)" ::: "memory");
}

// Monotone bijection float -> uint32 (order-preserving, invertible).
__device__ __forceinline__ unsigned f2key(float x) {
    unsigned u = __float_as_uint(x);
    return u ^ ((unsigned)((int)u >> 31) | 0x80000000u);
}
__device__ __forceinline__ float key2f(unsigned k) {
    unsigned u = (k & 0x80000000u) ? (k ^ 0x80000000u) : ~k;
    return __uint_as_float(u);
}

// Padded histogram index: +4 dwords per 16 bins spreads the per-lane b128
// scan reads (stride 20 dwords) across all banks.
__device__ __forceinline__ unsigned pidx(unsigned bin) {
    return bin + ((bin >> 4) << 2);
}

// 64-lane inclusive add-scan, pure VALU (DPP).
__device__ __forceinline__ unsigned wave_incl_scan(unsigned x) {
    int v = (int)x;
    v += __builtin_amdgcn_update_dpp(0, v, 0x111, 0xf, 0xf, false); // row_shr:1
    v += __builtin_amdgcn_update_dpp(0, v, 0x112, 0xf, 0xf, false); // row_shr:2
    v += __builtin_amdgcn_update_dpp(0, v, 0x114, 0xf, 0xf, false); // row_shr:4
    v += __builtin_amdgcn_update_dpp(0, v, 0x118, 0xf, 0xf, false); // row_shr:8
    v += __builtin_amdgcn_update_dpp(0, v, 0x142, 0xa, 0xf, false); // row_bcast:15
    v += __builtin_amdgcn_update_dpp(0, v, 0x143, 0xc, 0xf, false); // row_bcast:31
    return (unsigned)v;
}

// 256-bin scan+pick (4 bins/lane) — fallback rounds only.
__device__ __forceinline__ void scan_pick256(unsigned b0, unsigned b1, unsigned b2,
                                             unsigned b3, int lane, int rank_in,
                                             unsigned& digit, int& rank_out,
                                             int& cnteq_out) {
    unsigned s4 = b0 + b1 + b2 + b3;
    unsigned incl = wave_incl_scan(s4);
    int excl = (int)(incl - s4);
    bool found = (rank_in >= excl) && (rank_in < (int)incl);
    int rr = rank_in - excl;
    unsigned d = 4 * lane;
    unsigned beq = b0;
    if (found) {
        if (rr >= (int)b0) { rr -= (int)b0; d++; beq = b1;
            if (rr >= (int)b1) { rr -= (int)b1; d++; beq = b2;
                if (rr >= (int)b2) { rr -= (int)b2; d++; beq = b3; } } }
    }
    unsigned pack = (d << 24) | (beq << 12) | (unsigned)rr;
    unsigned long long bal = __ballot(found);
    int src = (int)__builtin_ctzll(bal);
    pack = (unsigned)__builtin_amdgcn_readlane((int)pack, src);
    digit = pack >> 24;
    cnteq_out = (int)((pack >> 12) & 0xfffu);
    rank_out = (int)(pack & 0xfffu);
}

__global__ __launch_bounds__(256)
void ktakes_kernel(const float* __restrict__ g, float* __restrict__ out) {
    const int tid  = threadIdx.x;
    const int wave = tid >> 6;
    const int lane = tid & 63;
    const int row  = blockIdx.x * 4 + wave;

    __shared__ unsigned H[4 * WSTRIDE];
    unsigned* hw  = H + wave * WSTRIDE;
    uint4*    hw4 = reinterpret_cast<uint4*>(hw);
    unsigned* Lb  = hw + LOFF;

    const float4* g4 = reinterpret_cast<const float4*>(g + (size_t)row * ROW_N);
    float4*       o4 = reinterpret_cast<float4*>(out + (size_t)row * ROW_N);

    // ---- issue all 8 loads, zero histogram under the vmcnt window ----
    float4 va[8];
#pragma unroll
    for (int j = 0; j < 8; ++j) va[j] = g4[j * 64 + lane];
    const uint4 z4 = {0u, 0u, 0u, 0u};
#pragma unroll
    for (int i = 0; i < 5; ++i) hw4[i * 64 + lane] = z4;   // dwords 0..1279
    wfence();

    // ---- convert + round-0 10-bit histogram (pipelined with load arrival) ----
    unsigned k[32];
#pragma unroll
    for (int j = 0; j < 8; ++j) {
        k[4*j+0] = f2key(va[j].x); k[4*j+1] = f2key(va[j].y);
        k[4*j+2] = f2key(va[j].z); k[4*j+3] = f2key(va[j].w);
        atomicAdd(&hw[pidx(k[4*j+0] >> 22)], 1u);
        atomicAdd(&hw[pidx(k[4*j+1] >> 22)], 1u);
        atomicAdd(&hw[pidx(k[4*j+2] >> 22)], 1u);
        atomicAdd(&hw[pidx(k[4*j+3] >> 22)], 1u);
    }
    wfence();

    // ---- scan 1024 bins: 16/lane at padded base 20*lane ----
    uint4 h0 = *reinterpret_cast<const uint4*>(&hw[20 * lane +  0]);
    uint4 h1 = *reinterpret_cast<const uint4*>(&hw[20 * lane +  4]);
    uint4 h2 = *reinterpret_cast<const uint4*>(&hw[20 * lane +  8]);
    uint4 h3 = *reinterpret_cast<const uint4*>(&hw[20 * lane + 12]);
    unsigned q0 = h0.x + h0.y + h0.z + h0.w;
    unsigned q1 = h1.x + h1.y + h1.z + h1.w;
    unsigned q2 = h2.x + h2.y + h2.z + h2.w;
    unsigned q3 = h3.x + h3.y + h3.z + h3.w;
    unsigned s16 = q0 + q1 + q2 + q3;
    unsigned incl = wave_incl_scan(s16);
    int excl = (int)(incl - s16);
    bool found = (ROW_K - 1 >= excl) && (ROW_K - 1 < (int)incl);
    int rr = (ROW_K - 1) - excl;
    unsigned d = 16 * lane;
    unsigned cnt = 0;
    if (found) {
        uint4 sel = h0;
        if (rr >= (int)q0) { rr -= (int)q0; d += 4; sel = h1;
            if (rr >= (int)q1) { rr -= (int)q1; d += 4; sel = h2;
                if (rr >= (int)q2) { rr -= (int)q2; d += 4; sel = h3; } } }
        cnt = sel.x;
        if (rr >= (int)sel.x) { rr -= (int)sel.x; d++; cnt = sel.y;
            if (rr >= (int)sel.y) { rr -= (int)sel.y; d++; cnt = sel.z;
                if (rr >= (int)sel.z) { rr -= (int)sel.z; d++; cnt = sel.w; } } }
    }
    {
        unsigned long long bal = __ballot(found);
        int src = (int)__builtin_ctzll(bal);
        unsigned pA = (d << 12) | (unsigned)rr;     // d:10b @12, rr:<=2047 @0
        pA  = (unsigned)__shfl((int)pA, src, 64);
        cnt = (unsigned)__shfl((int)cnt, src, 64);
        d  = pA >> 12;
        rr = (int)(pA & 0xfffu);
    }
    const int c1 = (int)cnt;              // count in selected 10-bit bin
    unsigned prefix = d << 22;
    int rank = rr;                        // rank within that bin

    unsigned Kth;
    int cnteq, m_rank;

    if (c1 <= 128) {
        // ---- ballot-compact survivors into Lb[0..c1) ----
        unsigned base = 0;
#pragma unroll
        for (int c = 0; c < 32; ++c) {
            bool mt = ((k[c] ^ prefix) >> 22) == 0;
            unsigned long long bal = __ballot(mt);
            if (mt) {
                unsigned pos = base +
                    (unsigned)__popcll(bal & ((1ull << lane) - 1ull));
                Lb[pos] = k[c];
            }
            base += (unsigned)__popcll(bal);
        }
        wfence();
        // ---- in-register ballot radix over low 22 bits, 2 keys/lane ----
        unsigned v0 = Lb[lane], v1 = Lb[64 + lane];
        bool a0 = (lane < c1), a1 = (64 + lane < c1);
        int r2 = rank;
#pragma unroll
        for (int bit = 21; bit >= 0; --bit) {
            bool z0 = a0 && (((v0 >> bit) & 1u) == 0u);
            bool z1 = a1 && (((v1 >> bit) & 1u) == 0u);
            unsigned long long bz0 = __ballot(z0);
            unsigned long long bz1 = __ballot(z1);
            int nz = __popcll(bz0) + __popcll(bz1);
            if (r2 < nz) { a0 = z0; a1 = z1; }
            else         { r2 -= nz; a0 = a0 && !z0; a1 = a1 && !z1; }
        }
        unsigned long long ba0 = __ballot(a0);
        unsigned long long ba1 = __ballot(a1);
        cnteq = __popcll(ba0) + __popcll(ba1);
        if (ba0) {
            int src = (int)__builtin_ctzll(ba0);
            Kth = (unsigned)__shfl((int)v0, src, 64);
        } else {
            int src = (int)__builtin_ctzll(ba1);
            Kth = (unsigned)__shfl((int)v1, src, 64);
        }
        m_rank = r2;
    } else {
        // ---- fallback (rare/adversarial): 8+8+6-bit rounds, 256-bin buffer ----
        unsigned dd;
        // round 1: bits 21..14
        hw4[lane] = z4; wfence();
#pragma unroll
        for (int c = 0; c < 32; ++c)
            if (((k[c] ^ prefix) >> 22) == 0)
                atomicAdd(&hw[(k[c] >> 14) & 255u], 1u);
        wfence();
        { uint4 h = hw4[lane];
          scan_pick256(h.x, h.y, h.z, h.w, lane, rank, dd, rank, cnteq); }
        prefix |= dd << 14;
        // round 2: bits 13..6
        hw4[lane] = z4; wfence();
#pragma unroll
        for (int c = 0; c < 32; ++c)
            if (((k[c] ^ prefix) >> 14) == 0)
                atomicAdd(&hw[(k[c] >> 6) & 255u], 1u);
        wfence();
        { uint4 h = hw4[lane];
          scan_pick256(h.x, h.y, h.z, h.w, lane, rank, dd, rank, cnteq); }
        prefix |= dd << 6;
        // round 3: bits 5..0 (bins 64..255 stay zero)
        hw4[lane] = z4; wfence();
#pragma unroll
        for (int c = 0; c < 32; ++c)
            if (((k[c] ^ prefix) >> 6) == 0)
                atomicAdd(&hw[k[c] & 63u], 1u);
        wfence();
        { uint4 h = hw4[lane];
          scan_pick256(h.x, h.y, h.z, h.w, lane, rank, dd, rank, cnteq); }
        prefix |= dd;
        Kth = prefix;
        m_rank = rank;
    }

    const int m = m_rank + 1;   // # of ==Kth elems to zero (lowest index first)

    // ---- build zero-mask ----
    unsigned zm = 0;
    if (cnteq == m) {
#pragma unroll
        for (int c = 0; c < 32; ++c)
            if (k[c] <= Kth) zm |= 1u << c;
    } else {
        // rare tie path: zero only first m equals in global index order
        int base = 0;
#pragma unroll
        for (int j = 0; j < 8; ++j) {
            int eqmask = 0, e = 0;
#pragma unroll
            for (int c = 0; c < 4; ++c) {
                bool q = (k[4*j+c] == Kth);
                eqmask |= (int)q << c; e += (int)q;
            }
            int incl2 = e;
#pragma unroll
            for (int off = 1; off < 64; off <<= 1) {
                int n = __shfl_up(incl2, off, 64);
                if (lane >= off) incl2 += n;
            }
            int excl2 = incl2 - e;
            int tot = __shfl(incl2, 63, 64);
            int pos = base + excl2;              // index order = (j, lane, c)
#pragma unroll
            for (int c = 0; c < 4; ++c) {
                if (eqmask & (1 << c)) {
                    if (pos < m) zm |= 1u << (4*j+c);
                    pos++;
                }
            }
            base += tot;
        }
#pragma unroll
        for (int c = 0; c < 32; ++c)
            if (k[c] < Kth) zm |= 1u << c;
    }

    // ---- write output (reconstruct floats from keys) ----
#pragma unroll
    for (int j = 0; j < 8; ++j) {
        float4 v;
        v.x = (zm >> (4*j+0)) & 1u ? 0.0f : key2f(k[4*j+0]);
        v.y = (zm >> (4*j+1)) & 1u ? 0.0f : key2f(k[4*j+1]);
        v.z = (zm >> (4*j+2)) & 1u ? 0.0f : key2f(k[4*j+2]);
        v.w = (zm >> (4*j+3)) & 1u ? 0.0f : key2f(k[4*j+3]);
        o4[j * 64 + lane] = v;
    }
}

extern "C" void kernel_launch(void* const* d_in, const int* in_sizes, int n_in,
                              void* d_out, int out_size, void* d_ws, size_t ws_size,
                              hipStream_t stream) {
    const float* g = (const float*)d_in[0];
    float* out = (float*)d_out;
    const int rows = in_sizes[0] / ROW_N;     // 32768, divisible by 4
    hipLaunchKernelGGL(ktakes_kernel, dim3(rows / 4), dim3(256), 0, stream, g, out);
}